// Round 15
// baseline (17.162 us; speedup 1.0000x reference)
//
#include <hip/hip_runtime.h>

#define L 4096
#define NT 256
#define C 16                  // elements per thread (one chunk per thread)
#define NC (NT + 4)           // chunk rows incl. 2 pads each side
#define SS 20                 // scan row stride in words (80B, 16B-aligned, bank-spread)

typedef unsigned int u32;
typedef unsigned long long u64;

static __device__ __forceinline__ u32 umax(u32 a, u32 b) { return a > b ? a : b; }

// One block per row. Exact greedy NMS via iterative local-max peeling.
// u32 key = bits(|x|)+1 (0 = inactive). Only a chunk's FIRST argmax can win
// (chunk width 16 <= 33, so its +-32 window covers the whole chunk). Ties:
// left blockers block on >=, right on > — exactly the stable argsort(-|x|)
// (ascending-index tie-break) order of the reference. Scans cached in LDS
// (SS=20 rows: om-indexed reads well bank-spread); TA in a separate
// stride-1 array (fixed-column TA reads at stride 20 were a deterministic
// 8-way bank conflict). Rescan only when the alive set actually changes;
// fully-dead chunks take a 9-store zero fast path.
__global__ __launch_bounds__(NT) void extrema_nms_kernel(const float* __restrict__ in,
                                                         float* __restrict__ out) {
    __shared__ u32 pfxS[NC * SS];  // [cc*SS + o]: prefix-max of chunk
    __shared__ u32 sfxS[NC * SS];  // [cc*SS + o]: suffix-max of chunk
    __shared__ u32 TAc[NC];        // chunk max, stride-1 (conflict-free)
    __shared__ u32 winmF[2 * NC];  // winner masks, double-buffered by parity
    __shared__ int flagsF[2];

    const int tid = threadIdx.x;
    const int cc = tid + 2;
    const int base = tid * C;
    const float* xrow = in + (size_t)blockIdx.x * L;

    // ---- pads (written once, never again) ----
    if (tid < 4 * SS) {                       // scan pad rows 0,1,NT+2,NT+3
        int rsel = tid / SS;
        int row = (rsel & 1) + ((rsel >> 1) ? (NT + 2) : 0);
        int col = tid % SS;
        pfxS[row * SS + col] = 0;
        sfxS[row * SS + col] = 0;
    }
    if (tid < 4) {                            // TAc + winm pads (both parities)
        int slot = (tid & 1) + ((tid >> 1) ? (NT + 2) : 0);
        TAc[slot] = 0;
        winmF[slot] = 0;
        winmF[NC + slot] = 0;
    }
    if (tid == 0) { flagsF[0] = 0; flagsF[1] = 0; }

    // ---- load own 16 x values + boundary neighbors ----
    float xv[C];
    #pragma unroll
    for (int k = 0; k < C; k += 4) {
        float4 f = *reinterpret_cast<const float4*>(xrow + base + k);
        xv[k] = f.x; xv[k + 1] = f.y; xv[k + 2] = f.z; xv[k + 3] = f.w;
    }
    float xl = (base > 0) ? xrow[base - 1] : 0.0f;
    float xr = (base + C < L) ? xrow[base + C] : 0.0f;

    // ---- extrema mask -> u32 keys ----
    // right[i] = (i<L-1) && x[i+1] >  x[i]; left[i] = (i==0) || x[i] <= x[i-1]
    u32 key[C];
    #pragma unroll
    for (int o = 0; o < C; ++o) {
        int i = base + o;
        float xi = xv[o];
        float xp = (o == 0) ? xl : xv[o - 1];
        float xn = (o == C - 1) ? xr : xv[o + 1];
        bool right = (i < L - 1) && (xn > xi);
        bool left  = (i == 0) || (xi <= xp);
        bool neg   = (xi <= 0.0f);
        bool ext = (right && left && neg) || (!right && !left && !neg);
        key[o] = ext ? ((__float_as_uint(xi) & 0x7fffffffu) + 1u) : 0u;
    }

    // ---- initial scans -> LDS (b128); run/om/alivem in registers ----
    u32 run, om, alivem = 0;
    {
        u32 pf[C], sf[C];
        u32 p = 0, nom = 0;
        #pragma unroll
        for (int o = 0; o < C; ++o) {
            u32 k = key[o];
            if (k) alivem |= (1u << o);
            if (k > p) { p = k; nom = (u32)o; }
            pf[o] = p;
        }
        u32 s = 0;
        #pragma unroll
        for (int o = C - 1; o >= 0; --o) { s = umax(s, key[o]); sf[o] = s; }
        u32* pr = &pfxS[cc * SS];
        u32* sr = &sfxS[cc * SS];
        #pragma unroll
        for (int k4 = 0; k4 < C; k4 += 4) {
            *reinterpret_cast<uint4*>(pr + k4) = make_uint4(pf[k4], pf[k4+1], pf[k4+2], pf[k4+3]);
            *reinterpret_cast<uint4*>(sr + k4) = make_uint4(sf[k4], sf[k4+1], sf[k4+2], sf[k4+3]);
        }
        TAc[cc] = p;
        run = p; om = nom;
    }
    u32 keptm = 0;
    __syncthreads();

    // ---- peeling rounds: 2 barriers per round ----
    for (int r = 0; r < 200; ++r) {
        // ===== detect: only the chunk's first argmax can win =====
        u32 wm = 0;
        if (run) {
            u32 bL = umax(sfxS[(cc - 2) * SS + om], TAc[cc - 1]); // blocks iff >= run
            u32 bR = umax(TAc[cc + 1], pfxS[(cc + 2) * SS + om]); // blocks iff >  run
            if (bL < run && bR <= run) wm = 1u << om;
        }
        winmF[(r & 1) * NC + cc] = wm;        // unconditional: no stale masks ever
        if (wm) { keptm |= wm; flagsF[r & 1] = 1; }   // same-value race benign
        __syncthreads();

        // ===== apply winners =====
        int go = flagsF[r & 1];
        u32 m0 = 0, m1 = 0, m3 = 0, m4 = 0;
        if (run) {
            const int pp = (r & 1) * NC;
            m0 = winmF[pp + cc - 2]; m1 = winmF[pp + cc - 1];
            m3 = winmF[pp + cc + 1]; m4 = winmF[pp + cc + 2];
        }
        if (tid == 0) flagsF[(r + 1) & 1] = 0;        // safe: 2 barriers since last read
        if (!go) break;                                // uniform: fixpoint reached
        // winner bits of chunks cc-2..cc+2 in the 80-bit space [base-32, base+47];
        // suppressed(o) iff any winner bit in [o, o+64]
        u64 W0 = (u64)m0 | ((u64)m1 << 16) | ((u64)wm << 32) | ((u64)m3 << 48);
        u32 W1 = m4;
        u32 supmask = 0;
        if (W0) { int h0 = 63 - __clzll(W0); supmask = (h0 >= 15) ? 0xffffu : ((2u << h0) - 1u); }
        if (W1) { int l1 = __ffs((int)W1) - 1; supmask |= ~((1u << l1) - 1u); }
        u32 newAlive = alivem & ~supmask;
        if (newAlive != alivem) {             // keys actually change
            alivem = newAlive;
            u32* pr = &pfxS[cc * SS];
            u32* sr = &sfxS[cc * SS];
            if (newAlive == 0) {              // full death: zero-store fast path
                uint4 z = make_uint4(0, 0, 0, 0);
                #pragma unroll
                for (int k4 = 0; k4 < C; k4 += 4) {
                    *reinterpret_cast<uint4*>(pr + k4) = z;
                    *reinterpret_cast<uint4*>(sr + k4) = z;
                }
                TAc[cc] = 0;
                run = 0; om = 0;
            } else {
                #pragma unroll
                for (int o = 0; o < C; ++o) key[o] = ((supmask >> o) & 1u) ? 0u : key[o];
                u32 pf[C], sf[C];
                u32 p = 0, nom = 0;
                #pragma unroll
                for (int o = 0; o < C; ++o) {
                    u32 k = key[o];
                    if (k > p) { p = k; nom = (u32)o; }
                    pf[o] = p;
                }
                u32 s = 0;
                #pragma unroll
                for (int o = C - 1; o >= 0; --o) { s = umax(s, key[o]); sf[o] = s; }
                #pragma unroll
                for (int k4 = 0; k4 < C; k4 += 4) {
                    *reinterpret_cast<uint4*>(pr + k4) = make_uint4(pf[k4], pf[k4+1], pf[k4+2], pf[k4+3]);
                    *reinterpret_cast<uint4*>(sr + k4) = make_uint4(sf[k4], sf[k4+1], sf[k4+2], sf[k4+3]);
                }
                TAc[cc] = p;
                run = p; om = nom;
            }
        }
        __syncthreads();
    }

    // ---- output straight from registers ----
    float* orow = out + (size_t)blockIdx.x * L;
    #pragma unroll
    for (int k = 0; k < C; k += 4) {
        float4 f;
        f.x = ((keptm >> (k + 0)) & 1u) ? xv[k + 0] : 0.0f;
        f.y = ((keptm >> (k + 1)) & 1u) ? xv[k + 1] : 0.0f;
        f.z = ((keptm >> (k + 2)) & 1u) ? xv[k + 2] : 0.0f;
        f.w = ((keptm >> (k + 3)) & 1u) ? xv[k + 3] : 0.0f;
        *reinterpret_cast<float4*>(orow + base + k) = f;
    }
}

extern "C" void kernel_launch(void* const* d_in, const int* in_sizes, int n_in,
                              void* d_out, int out_size, void* d_ws, size_t ws_size,
                              hipStream_t stream) {
    const float* in = (const float*)d_in[0];
    float* out = (float*)d_out;
    int rows = in_sizes[0] / L;   // 128
    extrema_nms_kernel<<<rows, NT, 0, stream>>>(in, out);
}

// Round 16
// 11.779 us; speedup vs baseline: 1.4570x; 1.4570x over previous
//
#include <hip/hip_runtime.h>

#define L 4096
#define NT 256
#define C 16                  // elements per thread (one chunk per thread)
#define NC (NT + 4)           // chunk rows incl. 2 pads each side
#define SS 20                 // scan row stride in words (80B, 16B-aligned)

typedef unsigned int u32;
typedef unsigned long long u64;

static __device__ __forceinline__ u32 umax(u32 a, u32 b) { return a > b ? a : b; }

// One block per row. Exact greedy NMS via iterative local-max peeling.
// u32 key = bits(|x|)+1 (0 = inactive). Only a chunk's FIRST argmax can win
// (chunk width 16 <= 33, so at most one winner/chunk/round — argmax-only is
// round-optimal). Ties: left blockers block on >=, right on > — exactly the
// stable argsort(-|x|) order. Scans cached in LDS row-major, rewritten only
// when a chunk's keys change (8 x ds_write_b128). TA folded into pfx[16].
__global__ __launch_bounds__(NT) void extrema_nms_kernel(const float* __restrict__ in,
                                                         float* __restrict__ out) {
    __shared__ u32 pfxS[NC * SS];  // [cc*SS + o]: o in 0..15 prefix-max, o=16 TA
    __shared__ u32 sfxS[NC * SS];  // [cc*SS + o]: o in 0..15 suffix-max
    __shared__ u32 winmF[2 * NC];  // winner masks, double-buffered by parity
    __shared__ int flagsF[2];

    const int tid = threadIdx.x;
    const int cc = tid + 2;
    const int base = tid * C;
    const float* xrow = in + (size_t)blockIdx.x * L;

    // ---- pads (written once, never again) ----
    if (tid < 4 * SS) {                       // rows 0,1,NT+2,NT+3
        int rsel = tid / SS;
        int row = (rsel & 1) + ((rsel >> 1) ? (NT + 2) : 0);
        int col = tid % SS;
        pfxS[row * SS + col] = 0;
        sfxS[row * SS + col] = 0;
    }
    if (tid < 4) {                            // winm pads, both parities
        int slot = (tid & 1) + ((tid >> 1) ? (NT + 2) : 0);
        winmF[slot] = 0;
        winmF[NC + slot] = 0;
    }
    if (tid == 0) { flagsF[0] = 0; flagsF[1] = 0; }

    // ---- load own 16 x values + boundary neighbors ----
    float xv[C];
    #pragma unroll
    for (int k = 0; k < C; k += 4) {
        float4 f = *reinterpret_cast<const float4*>(xrow + base + k);
        xv[k] = f.x; xv[k + 1] = f.y; xv[k + 2] = f.z; xv[k + 3] = f.w;
    }
    float xl = (base > 0) ? xrow[base - 1] : 0.0f;
    float xr = (base + C < L) ? xrow[base + C] : 0.0f;

    // ---- extrema mask -> u32 keys ----
    // right[i] = (i<L-1) && x[i+1] >  x[i]; left[i] = (i==0) || x[i] <= x[i-1]
    u32 key[C];
    #pragma unroll
    for (int o = 0; o < C; ++o) {
        int i = base + o;
        float xi = xv[o];
        float xp = (o == 0) ? xl : xv[o - 1];
        float xn = (o == C - 1) ? xr : xv[o + 1];
        bool right = (i < L - 1) && (xn > xi);
        bool left  = (i == 0) || (xi <= xp);
        bool neg   = (xi <= 0.0f);
        bool ext = (right && left && neg) || (!right && !left && !neg);
        key[o] = ext ? ((__float_as_uint(xi) & 0x7fffffffu) + 1u) : 0u;
    }

    // ---- initial scans -> LDS (b128), run/om in registers ----
    u32 run, om;
    {
        u32 pf[C], sf[C];
        u32 p = 0, nom = 0;
        #pragma unroll
        for (int o = 0; o < C; ++o) { u32 k = key[o]; if (k > p) { p = k; nom = (u32)o; } pf[o] = p; }
        u32 s = 0;
        #pragma unroll
        for (int o = C - 1; o >= 0; --o) { s = umax(s, key[o]); sf[o] = s; }
        u32* pr = &pfxS[cc * SS];
        u32* sr = &sfxS[cc * SS];
        #pragma unroll
        for (int k4 = 0; k4 < C; k4 += 4) {
            *reinterpret_cast<uint4*>(pr + k4) = make_uint4(pf[k4], pf[k4+1], pf[k4+2], pf[k4+3]);
            *reinterpret_cast<uint4*>(sr + k4) = make_uint4(sf[k4], sf[k4+1], sf[k4+2], sf[k4+3]);
        }
        pr[16] = p;                           // TA
        run = p; om = nom;
    }
    u32 keptm = 0;
    __syncthreads();

    // ---- peeling rounds: 2 barriers per round ----
    for (int r = 0; r < 200; ++r) {
        // ===== detect: only the chunk's first argmax can win =====
        u32 wm = 0;
        if (run) {
            u32 bL = umax(sfxS[(cc - 2) * SS + om], pfxS[(cc - 1) * SS + 16]); // >= blocks
            u32 bR = umax(pfxS[(cc + 1) * SS + 16], pfxS[(cc + 2) * SS + om]); // >  blocks
            if (bL < run && bR <= run) wm = 1u << om;
        }
        winmF[(r & 1) * NC + cc] = wm;        // unconditional: no stale masks ever
        if (wm) { keptm |= wm; flagsF[r & 1] = 1; }   // same-value race benign
        __syncthreads();

        // ===== apply winners =====
        int go = flagsF[r & 1];
        u32 m0 = 0, m1 = 0, m3 = 0, m4 = 0;
        if (run) {
            const int pp = (r & 1) * NC;
            m0 = winmF[pp + cc - 2]; m1 = winmF[pp + cc - 1];
            m3 = winmF[pp + cc + 1]; m4 = winmF[pp + cc + 2];
        }
        if (tid == 0) flagsF[(r + 1) & 1] = 0;        // safe: 2 barriers from last read
        if (!go) break;                                // uniform: fixpoint reached
        // winner bits of chunks cc-2..cc+2 in the 80-bit space [base-32, base+47];
        // suppressed(o) iff any winner bit in [o, o+64]
        u64 W0 = (u64)m0 | ((u64)m1 << 16) | ((u64)wm << 32) | ((u64)m3 << 48);
        u32 W1 = m4;
        u32 supmask = 0;
        if (W0) { int h0 = 63 - __clzll(W0); supmask = (h0 >= 15) ? 0xffffu : ((2u << h0) - 1u); }
        if (W1) { int l1 = __ffs((int)W1) - 1; supmask |= ~((1u << l1) - 1u); }
        supmask &= 0xffffu;
        if (run && supmask) {                 // keys change -> rewrite scans
            #pragma unroll
            for (int o = 0; o < C; ++o) key[o] = ((supmask >> o) & 1u) ? 0u : key[o];
            u32 pf[C], sf[C];
            u32 p = 0, nom = 0;
            #pragma unroll
            for (int o = 0; o < C; ++o) { u32 k = key[o]; if (k > p) { p = k; nom = (u32)o; } pf[o] = p; }
            u32 s = 0;
            #pragma unroll
            for (int o = C - 1; o >= 0; --o) { s = umax(s, key[o]); sf[o] = s; }
            u32* pr = &pfxS[cc * SS];
            u32* sr = &sfxS[cc * SS];
            #pragma unroll
            for (int k4 = 0; k4 < C; k4 += 4) {
                *reinterpret_cast<uint4*>(pr + k4) = make_uint4(pf[k4], pf[k4+1], pf[k4+2], pf[k4+3]);
                *reinterpret_cast<uint4*>(sr + k4) = make_uint4(sf[k4], sf[k4+1], sf[k4+2], sf[k4+3]);
            }
            pr[16] = p;
            run = p; om = nom;
        }
        __syncthreads();
    }

    // ---- output straight from registers ----
    float* orow = out + (size_t)blockIdx.x * L;
    #pragma unroll
    for (int k = 0; k < C; k += 4) {
        float4 f;
        f.x = ((keptm >> (k + 0)) & 1u) ? xv[k + 0] : 0.0f;
        f.y = ((keptm >> (k + 1)) & 1u) ? xv[k + 1] : 0.0f;
        f.z = ((keptm >> (k + 2)) & 1u) ? xv[k + 2] : 0.0f;
        f.w = ((keptm >> (k + 3)) & 1u) ? xv[k + 3] : 0.0f;
        *reinterpret_cast<float4*>(orow + base + k) = f;
    }
}

extern "C" void kernel_launch(void* const* d_in, const int* in_sizes, int n_in,
                              void* d_out, int out_size, void* d_ws, size_t ws_size,
                              hipStream_t stream) {
    const float* in = (const float*)d_in[0];
    float* out = (float*)d_out;
    int rows = in_sizes[0] / L;   // 128
    extrema_nms_kernel<<<rows, NT, 0, stream>>>(in, out);
}